// Round 1
// baseline (509.122 us; speedup 1.0000x reference)
//
#include <hip/hip_runtime.h>

// ---------------- constants ----------------
// B=8, C=32, CO=32, NIN=16, NOUT=10, D1=D2=512, NRC=1344
// outputs (fp32, concatenated): zw0[8,32,512,16] zw1[8,32,512,512] zw2[8,32,10,512]
//                               u0[8,32,512] u1[8,32,512] u2[8,32,10]
#define OUT_ZW1 2097152u
#define OUT_ZW2 69206016u
#define OUT_U0  70516736u
#define OUT_U1  70647808u
#define OUT_U2  70778880u

// workspace layout (floats) — ~13.3 MB total
#define WS_RM1      0u
#define WS_CM1      131072u
#define WS_CM0      262144u
#define WS_RM2      393216u
#define WS_CM2      524288u
#define WS_RC       526848u
#define WS_TW0      537600u
#define WS_TB0      541696u
#define WS_TL1      541952u
#define WS_TBIAS1   542208u
#define WS_TFIN     542464u
#define WS_RTERM    545024u
#define WS_CTERM    676096u
#define WS_W0T      807168u
#define WS_WT_RPT   2904320u
#define WS_WT_B0    3199232u
#define WS_WT_FIN   3217664u
#define WS_WT_L1    3330304u
#define WS_MEMSET_FLOATS 537600u

static __device__ __forceinline__ float wave_reduce(float v) {
#pragma unroll
  for (int off = 32; off > 0; off >>= 1) v += __shfl_down(v, off);
  return v;
}

__global__ void ktrans(const float* __restrict__ A, float* __restrict__ At, int R, int C) {
  int idx = blockIdx.x * 256 + threadIdx.x;
  if (idx >= R * C) return;
  int r = idx / C, c = idx - r * C;
  At[(size_t)c * R + r] = A[idx];
}

__global__ __launch_bounds__(256) void ktransw0(const float* __restrict__ w0,
                                                float* __restrict__ w0T) {
  int bc = blockIdx.x;
  int b = bc >> 5, c = bc & 31;
  for (int k = 0; k < 16; ++k)
    for (int d = threadIdx.x; d < 512; d += 256)
      w0T[((size_t)(b * 512 + c * 16 + k)) * 512 + d] = w0[((size_t)bc * 512 + d) * 16 + k];
}

__global__ __launch_bounds__(256) void kstats(
    const float* __restrict__ w0, const float* __restrict__ w2,
    const float* __restrict__ b0, const float* __restrict__ b1,
    const float* __restrict__ b2, float* __restrict__ cm0, float* __restrict__ rm2,
    float* __restrict__ cm2, float* __restrict__ rc) {
  int bc = blockIdx.x;
  int b = bc >> 5, c = bc & 31;
  int tid = threadIdx.x, lane = tid & 63;
  __shared__ float sred[16];
  __shared__ float stot;
  float* rcb = rc + b * 1344;

  if (tid < 16) sred[tid] = 0.f;
  if (tid == 0) stot = 0.f;
  __syncthreads();
  {
    float rm0p[16];
#pragma unroll
    for (int k = 0; k < 16; ++k) rm0p[k] = 0.f;
    float tot = 0.f;
    for (int d = tid; d < 512; d += 256) {
      const float4* p = (const float4*)(w0 + ((size_t)bc * 512 + d) * 16);
      float s = 0.f;
#pragma unroll
      for (int q = 0; q < 4; ++q) {
        float4 v = p[q];
        s += v.x + v.y + v.z + v.w;
        rm0p[q * 4 + 0] += v.x; rm0p[q * 4 + 1] += v.y;
        rm0p[q * 4 + 2] += v.z; rm0p[q * 4 + 3] += v.w;
      }
      cm0[(size_t)bc * 512 + d] = s * (1.f / 16.f);
      tot += s;
    }
#pragma unroll
    for (int k = 0; k < 16; ++k) {
      float r = wave_reduce(rm0p[k]);
      if (lane == 0) atomicAdd(&sred[k], r);
    }
    float rt = wave_reduce(tot);
    if (lane == 0) atomicAdd(&stot, rt);
  }
  __syncthreads();
  if (tid < 16) rcb[192 + c * 16 + tid] = sred[tid] * (1.f / 512.f);
  if (tid == 0) rcb[c] = stot * (1.f / 8192.f);
  __syncthreads();

  if (tid < 10) sred[tid] = 0.f;
  if (tid == 0) stot = 0.f;
  __syncthreads();
  {
    float cm2p[10];
#pragma unroll
    for (int k = 0; k < 10; ++k) cm2p[k] = 0.f;
    float tot = 0.f;
    for (int d = tid; d < 512; d += 256) {
      float s = 0.f;
#pragma unroll
      for (int k = 0; k < 10; ++k) {
        float v = w2[((size_t)bc * 10 + k) * 512 + d];
        s += v; cm2p[k] += v;
      }
      rm2[(size_t)bc * 512 + d] = s * 0.1f;
      tot += s;
    }
#pragma unroll
    for (int k = 0; k < 10; ++k) {
      float r = wave_reduce(cm2p[k]);
      if (lane == 0) atomicAdd(&sred[k], r);
    }
    float rt = wave_reduce(tot);
    if (lane == 0) atomicAdd(&stot, rt);
  }
  __syncthreads();
  if (tid < 10) {
    float m = sred[tid] * (1.f / 512.f);
    cm2[bc * 10 + tid] = m;
    rcb[704 + c * 10 + tid] = m;
  }
  if (tid == 0) rcb[64 + c] = stot * (1.f / 5120.f);
  __syncthreads();

  if (tid < 2) sred[tid] = 0.f;
  __syncthreads();
  {
    float t0 = 0.f, t1 = 0.f;
    for (int d = tid; d < 512; d += 256) {
      t0 += b0[(size_t)bc * 512 + d];
      t1 += b1[(size_t)bc * 512 + d];
    }
    t0 = wave_reduce(t0); t1 = wave_reduce(t1);
    if (lane == 0) { atomicAdd(&sred[0], t0); atomicAdd(&sred[1], t1); }
  }
  __syncthreads();
  if (tid == 0) {
    rcb[96 + c] = sred[0] * (1.f / 512.f);
    rcb[128 + c] = sred[1] * (1.f / 512.f);
  }

  float vb2 = 0.f;
  if (tid < 10) {
    vb2 = b2[bc * 10 + tid];
    rcb[1024 + c * 10 + tid] = vb2;
  }
  if (tid < 64) {
    float s = wave_reduce(vb2);
    if (tid == 0) rcb[160 + c] = s * 0.1f;
  }
}

__global__ __launch_bounds__(256) void kw1stats(const float* __restrict__ w1,
                                                float* __restrict__ rm1,
                                                float* __restrict__ cm1,
                                                float* __restrict__ rc) {
  int idx = blockIdx.x;
  int bc = idx >> 2, hc = idx & 3;
  int b = bc >> 5, c = bc & 31;
  int tid = threadIdx.x, lane = tid & 63, wid = tid >> 6;
  __shared__ float rpart[512];
  const float* base = w1 + (size_t)bc * 262144;
  float col0 = 0.f, col1 = 0.f;
  for (int hl = 0; hl < 128; ++hl) {
    int h = hc * 128 + hl;
    float x0 = base[h * 512 + tid];
    float x1 = base[h * 512 + tid + 256];
    col0 += x0; col1 += x1;
    float r = wave_reduce(x0 + x1);
    if (lane == 0) rpart[hl * 4 + wid] = r;
  }
  __syncthreads();
  if (tid < 128) {
    float s = rpart[tid * 4] + rpart[tid * 4 + 1] + rpart[tid * 4 + 2] + rpart[tid * 4 + 3];
    cm1[(size_t)bc * 512 + hc * 128 + tid] = s * (1.f / 512.f);
  }
  atomicAdd(&rm1[(size_t)bc * 512 + tid], col0);
  atomicAdd(&rm1[(size_t)bc * 512 + tid + 256], col1);
  float bt = wave_reduce(col0 + col1);
  if (lane == 0) atomicAdd(&rc[b * 1344 + 32 + c], bt * (1.f / 262144.f));
}

__global__ void kfin(float* __restrict__ rm1) {
  int i = blockIdx.x * 256 + threadIdx.x;
  rm1[i] *= (1.f / 512.f);
}

__global__ __launch_bounds__(256) void krcgemm(
    const float* __restrict__ rc,
    const float* __restrict__ W_w0_rc, const float* __restrict__ B_w0_rc,
    const float* __restrict__ W_b0_rc, const float* __restrict__ B_b0_rc,
    const float* __restrict__ W_l1_rc, const float* __restrict__ B_l1_rc,
    const float* __restrict__ W_bias1_rc, const float* __restrict__ B_bias1_rc,
    const float* __restrict__ W_fin_rc, const float* __restrict__ B_fin_rc,
    const float* __restrict__ W_bfin_rc, const float* __restrict__ B_bfin_rc,
    float* __restrict__ t_w0, float* __restrict__ t_b0, float* __restrict__ t_l1,
    float* __restrict__ t_bias1, float* __restrict__ t_fin, float* __restrict__ u2out) {
  int blk = blockIdx.x;
  int b = blk / 312;
  int tid = threadIdx.x, lane = tid & 63, wid = tid >> 6;
  int r = (blk % 312) * 4 + wid;
  __shared__ float rcs[1344];
  for (int i = tid; i < 1344; i += 256) rcs[i] = rc[b * 1344 + i];
  __syncthreads();
  const float* W; const float* Bb; float* dst; int row;
  if (r < 512)      { W = W_w0_rc;    Bb = B_w0_rc;    row = r;       dst = t_w0 + b * 512; }
  else if (r < 544) { W = W_b0_rc;    Bb = B_b0_rc;    row = r - 512; dst = t_b0 + b * 32; }
  else if (r < 576) { W = W_l1_rc;    Bb = B_l1_rc;    row = r - 544; dst = t_l1 + b * 32; }
  else if (r < 608) { W = W_bias1_rc; Bb = B_bias1_rc; row = r - 576; dst = t_bias1 + b * 32; }
  else if (r < 928) { W = W_fin_rc;   Bb = B_fin_rc;   row = r - 608; dst = t_fin + b * 320; }
  else              { W = W_bfin_rc;  Bb = B_bfin_rc;  row = r - 928; dst = u2out + b * 320; }
  const float* wr = W + (size_t)row * 1344;
  float acc = 0.f;
  for (int j = lane; j < 1344; j += 64) acc += wr[j] * rcs[j];
  acc = wave_reduce(acc);
  if (lane == 0) dst[row] = acc + Bb[row];
}

__global__ __launch_bounds__(256) void krterm(
    const float* __restrict__ rm1, const float* __restrict__ cm0,
    const float* __restrict__ b0, const float* __restrict__ w0T,
    const float* __restrict__ W_l1_r, const float* __restrict__ B_l1_r,
    float* __restrict__ rterm) {
  int o = blockIdx.y, b = blockIdx.z;
  int w = blockIdx.x * 256 + threadIdx.x;
  const float* Wr = W_l1_r + (size_t)o * 608;
  float acc = 0.f;
#pragma unroll 4
  for (int i = 0; i < 32; ++i) acc += Wr[i] * rm1[((size_t)b * 32 + i) * 512 + w];
#pragma unroll 4
  for (int i = 0; i < 32; ++i) acc += Wr[32 + i] * cm0[((size_t)b * 32 + i) * 512 + w];
#pragma unroll 4
  for (int i = 0; i < 32; ++i) acc += Wr[64 + i] * b0[((size_t)b * 32 + i) * 512 + w];
#pragma unroll 8
  for (int i = 0; i < 512; ++i) acc += Wr[96 + i] * w0T[((size_t)b * 512 + i) * 512 + w];
  rterm[((size_t)b * 32 + o) * 512 + w] = acc + B_l1_r[o];
}

__global__ __launch_bounds__(256) void kcterm(
    const float* __restrict__ cm1, const float* __restrict__ b1,
    const float* __restrict__ rm2, const float* __restrict__ w2,
    const float* __restrict__ W_l1_c, const float* __restrict__ B_l1_c,
    const float* __restrict__ B_l1, const float* __restrict__ t_l1,
    const float* __restrict__ W_bias1, const float* __restrict__ B_bias1,
    const float* __restrict__ t_bias1,
    float* __restrict__ cterm_full, float* __restrict__ u1out) {
  int o = blockIdx.y, b = blockIdx.z;
  int h = blockIdx.x * 256 + threadIdx.x;
  const float* Wc = W_l1_c + (size_t)o * 416;
  const float* Wu = W_bias1 + (size_t)o * 416;
  float ac = 0.f, au = 0.f;
#pragma unroll 4
  for (int i = 0; i < 32; ++i) {
    float x = cm1[((size_t)b * 32 + i) * 512 + h];
    ac += Wc[i] * x; au += Wu[i] * x;
  }
#pragma unroll 4
  for (int i = 0; i < 32; ++i) {
    float x = b1[((size_t)b * 32 + i) * 512 + h];
    ac += Wc[32 + i] * x; au += Wu[32 + i] * x;
  }
#pragma unroll 4
  for (int i = 0; i < 32; ++i) {
    float x = rm2[((size_t)b * 32 + i) * 512 + h];
    ac += Wc[64 + i] * x; au += Wu[64 + i] * x;
  }
#pragma unroll 8
  for (int i = 0; i < 320; ++i) {
    float x = w2[((size_t)b * 320 + i) * 512 + h];
    ac += Wc[96 + i] * x; au += Wu[96 + i] * x;
  }
  cterm_full[((size_t)b * 32 + o) * 512 + h] = ac + B_l1_c[o] + B_l1[o] + t_l1[b * 32 + o];
  u1out[((size_t)b * 32 + o) * 512 + h] = au + B_bias1[o] + t_bias1[b * 32 + o];
}

__global__ __launch_bounds__(256) void kz0(
    const float* __restrict__ w0T, const float* __restrict__ rm1,
    const float* __restrict__ b0, const float* __restrict__ Wt_rpt,
    const float* __restrict__ B_rpt, const float* __restrict__ Wt_b0,
    const float* __restrict__ B_b0w, const float* __restrict__ t_w0,
    const float* __restrict__ t_b0, float* __restrict__ out) {
  int oc = blockIdx.y, b = blockIdx.z;
  int d = blockIdx.x * 256 + threadIdx.x;
  bool isZ = oc < 64;
  int o0 = isZ ? oc * 8 : (oc - 64) * 8;
  int stride = isZ ? 512 : 32;
  const float* W = isZ ? Wt_rpt : Wt_b0;
  float acc[8] = {0, 0, 0, 0, 0, 0, 0, 0};
  for (int i = 0; i < 512; ++i) {
    float x = w0T[((size_t)b * 512 + i) * 512 + d];
    const float* wp = W + (size_t)i * stride + o0;
#pragma unroll
    for (int oo = 0; oo < 8; ++oo) acc[oo] += wp[oo] * x;
  }
#pragma unroll 4
  for (int i = 0; i < 32; ++i) {
    float x = rm1[((size_t)b * 32 + i) * 512 + d];
    const float* wp = W + (size_t)(512 + i) * stride + o0;
#pragma unroll
    for (int oo = 0; oo < 8; ++oo) acc[oo] += wp[oo] * x;
  }
#pragma unroll 4
  for (int i = 0; i < 32; ++i) {
    float x = b0[((size_t)b * 32 + i) * 512 + d];
    const float* wp = W + (size_t)(544 + i) * stride + o0;
#pragma unroll
    for (int oo = 0; oo < 8; ++oo) acc[oo] += wp[oo] * x;
  }
  if (isZ) {
#pragma unroll
    for (int oo = 0; oo < 8; ++oo) {
      int o = o0 + oo, co = o >> 4, k = o & 15;
      out[(((size_t)b * 32 + co) * 512 + d) * 16 + k] = acc[oo] + B_rpt[o] + t_w0[b * 512 + o];
    }
  } else {
#pragma unroll
    for (int oo = 0; oo < 8; ++oo) {
      int o = o0 + oo;
      out[OUT_U0 + ((size_t)b * 32 + o) * 512 + d] = acc[oo] + B_b0w[o] + t_b0[b * 32 + o];
    }
  }
}

__global__ __launch_bounds__(256) void kzf(
    const float* __restrict__ w2, const float* __restrict__ cm1,
    const float* __restrict__ Wt_fin, const float* __restrict__ B_fin,
    const float* __restrict__ t_fin, float* __restrict__ out) {
  int oc = blockIdx.y, b = blockIdx.z;
  int d = blockIdx.x * 256 + threadIdx.x;
  int o0 = oc * 8;
  float acc[8] = {0, 0, 0, 0, 0, 0, 0, 0};
  for (int i = 0; i < 320; ++i) {
    float x = w2[((size_t)b * 320 + i) * 512 + d];
    const float* wp = Wt_fin + (size_t)i * 320 + o0;
#pragma unroll
    for (int oo = 0; oo < 8; ++oo) acc[oo] += wp[oo] * x;
  }
#pragma unroll 4
  for (int i = 0; i < 32; ++i) {
    float x = cm1[((size_t)b * 32 + i) * 512 + d];
    const float* wp = Wt_fin + (size_t)(320 + i) * 320 + o0;
#pragma unroll
    for (int oo = 0; oo < 8; ++oo) acc[oo] += wp[oo] * x;
  }
#pragma unroll
  for (int oo = 0; oo < 8; ++oo) {
    int o = o0 + oo;
    out[OUT_ZW2 + ((size_t)b * 320 + o) * 512 + d] = acc[oo] + B_fin[o] + t_fin[b * 320 + o];
  }
}

__global__ __launch_bounds__(256) void kzw1(
    const float* __restrict__ w1, const float* __restrict__ Wt_l1,
    const float* __restrict__ rterm, const float* __restrict__ cterm,
    float* __restrict__ out) {
  int h = blockIdx.x, b = blockIdx.y;
  int t = threadIdx.x;
  float2 acc[32];
#pragma unroll
  for (int o = 0; o < 32; ++o) acc[o] = make_float2(0.f, 0.f);
  const float* src = w1 + ((size_t)b * 32 * 512 + h) * 512 + 2 * t;
#pragma unroll 4
  for (int i = 0; i < 32; ++i) {
    float2 x = *(const float2*)(src + (size_t)i * 262144);
    const float* wp = Wt_l1 + i * 32;
#pragma unroll
    for (int o = 0; o < 32; ++o) {
      acc[o].x += wp[o] * x.x;
      acc[o].y += wp[o] * x.y;
    }
  }
  size_t obase = (size_t)OUT_ZW1 + ((size_t)b * 32 * 512 + h) * 512 + 2 * t;
#pragma unroll
  for (int o = 0; o < 32; ++o) {
    float cf = cterm[((size_t)b * 32 + o) * 512 + h];
    float2 rt = *(const float2*)(rterm + ((size_t)b * 32 + o) * 512 + 2 * t);
    float2 res = make_float2(acc[o].x + rt.x + cf, acc[o].y + rt.y + cf);
    *(float2*)(out + obase + (size_t)o * 262144) = res;
  }
}

extern "C" void kernel_launch(void* const* d_in, const int* in_sizes, int n_in,
                              void* d_out, int out_size, void* d_ws, size_t ws_size,
                              hipStream_t stream) {
  const float* w0 = (const float*)d_in[0];
  const float* w1 = (const float*)d_in[1];
  const float* w2 = (const float*)d_in[2];
  const float* b0 = (const float*)d_in[3];
  const float* b1 = (const float*)d_in[4];
  const float* b2 = (const float*)d_in[5];
  const float* W_w0_rpt = (const float*)d_in[6];
  const float* B_w0_rpt = (const float*)d_in[7];
  const float* W_w0_rc = (const float*)d_in[8];
  const float* B_w0_rc = (const float*)d_in[9];
  const float* W_b0 = (const float*)d_in[10];
  const float* B_b0 = (const float*)d_in[11];
  const float* W_b0_rc = (const float*)d_in[12];
  const float* B_b0_rc = (const float*)d_in[13];
  const float* W_l1 = (const float*)d_in[14];
  const float* B_l1 = (const float*)d_in[15];
  const float* W_l1_rc = (const float*)d_in[16];
  const float* B_l1_rc = (const float*)d_in[17];
  const float* W_l1_r = (const float*)d_in[18];
  const float* B_l1_r = (const float*)d_in[19];
  const float* W_l1_c = (const float*)d_in[20];
  const float* B_l1_c = (const float*)d_in[21];
  const float* W_bias1 = (const float*)d_in[22];
  const float* B_bias1 = (const float*)d_in[23];
  const float* W_bias1_rc = (const float*)d_in[24];
  const float* B_bias1_rc = (const float*)d_in[25];
  const float* W_fin_cpt = (const float*)d_in[26];
  const float* B_fin_cpt = (const float*)d_in[27];
  const float* W_fin_rc = (const float*)d_in[28];
  const float* B_fin_rc = (const float*)d_in[29];
  const float* W_bfin_rc = (const float*)d_in[30];
  const float* B_bfin_rc = (const float*)d_in[31];
  float* ws = (float*)d_ws;
  float* out = (float*)d_out;

  hipMemsetAsync(d_ws, 0, WS_MEMSET_FLOATS * sizeof(float), stream);

  ktrans<<<dim3((512 * 576 + 255) / 256), 256, 0, stream>>>(W_w0_rpt, ws + WS_WT_RPT, 512, 576);
  ktrans<<<dim3((32 * 576 + 255) / 256), 256, 0, stream>>>(W_b0, ws + WS_WT_B0, 32, 576);
  ktrans<<<dim3((320 * 352 + 255) / 256), 256, 0, stream>>>(W_fin_cpt, ws + WS_WT_FIN, 320, 352);
  ktrans<<<dim3((32 * 32 + 255) / 256), 256, 0, stream>>>(W_l1, ws + WS_WT_L1, 32, 32);
  ktransw0<<<dim3(256), 256, 0, stream>>>(w0, ws + WS_W0T);

  kstats<<<dim3(256), 256, 0, stream>>>(w0, w2, b0, b1, b2, ws + WS_CM0, ws + WS_RM2,
                                        ws + WS_CM2, ws + WS_RC);
  kw1stats<<<dim3(1024), 256, 0, stream>>>(w1, ws + WS_RM1, ws + WS_CM1, ws + WS_RC);
  kfin<<<dim3(512), 256, 0, stream>>>(ws + WS_RM1);

  krcgemm<<<dim3(8 * 312), 256, 0, stream>>>(
      ws + WS_RC, W_w0_rc, B_w0_rc, W_b0_rc, B_b0_rc, W_l1_rc, B_l1_rc, W_bias1_rc,
      B_bias1_rc, W_fin_rc, B_fin_rc, W_bfin_rc, B_bfin_rc, ws + WS_TW0, ws + WS_TB0,
      ws + WS_TL1, ws + WS_TBIAS1, ws + WS_TFIN, out + OUT_U2);

  krterm<<<dim3(2, 32, 8), 256, 0, stream>>>(ws + WS_RM1, ws + WS_CM0, b0, ws + WS_W0T,
                                             W_l1_r, B_l1_r, ws + WS_RTERM);
  kcterm<<<dim3(2, 32, 8), 256, 0, stream>>>(ws + WS_CM1, b1, ws + WS_RM2, w2, W_l1_c,
                                             B_l1_c, B_l1, ws + WS_TL1, W_bias1, B_bias1,
                                             ws + WS_TBIAS1, ws + WS_CTERM, out + OUT_U1);
  kz0<<<dim3(2, 68, 8), 256, 0, stream>>>(ws + WS_W0T, ws + WS_RM1, b0, ws + WS_WT_RPT,
                                          B_w0_rpt, ws + WS_WT_B0, B_b0, ws + WS_TW0,
                                          ws + WS_TB0, out);
  kzf<<<dim3(2, 40, 8), 256, 0, stream>>>(w2, ws + WS_CM1, ws + WS_WT_FIN, B_fin_cpt,
                                          ws + WS_TFIN, out);
  kzw1<<<dim3(512, 8), 256, 0, stream>>>(w1, ws + WS_WT_L1, ws + WS_RTERM, ws + WS_CTERM,
                                         out);
  (void)in_sizes; (void)n_in; (void)out_size; (void)ws_size;
}